// Round 11
// baseline (129.366 us; speedup 1.0000x reference)
//
#include <hip/hip_runtime.h>
#include <math.h>

#define Hh 128
#define Ww 128
#define HW (Hh*Ww)
#define Bn 4
#define Cn 64
#define On 64
#define KP 200                // LDS A-row stride (shorts): 192 data + 8 pad
                              // (==0 mod 8 for 16B ds_read_b128; row stride
                              //  100 dw == 4 mod 32 banks -> 2-way max = free)
#define OMP 66                // padded px stride for sOM (f16), 64 px
#define NBLK 1024             // dcn grid (half-row blocks)

typedef __attribute__((ext_vector_type(8))) short bf16x8;
typedef __attribute__((ext_vector_type(4))) float f32x4;
typedef __attribute__((ext_vector_type(8))) unsigned short u16x8;
typedef __attribute__((ext_vector_type(4))) unsigned u32x4;

// fp32 -> bf16 round-to-nearest-even
static __device__ __forceinline__ unsigned short f2bf(float f) {
    unsigned u = __builtin_bit_cast(unsigned, f);
    u += 0x7FFFu + ((u >> 16) & 1u);
    return (unsigned short)(u >> 16);
}
static __device__ __forceinline__ short f2h(float f) {
    _Float16 h = (_Float16)f;
    return __builtin_bit_cast(short, h);
}
static __device__ __forceinline__ float h2f(short s) {
    return (float)__builtin_bit_cast(_Float16, s);
}
static __device__ __forceinline__ float h2fu(unsigned short s) {
    return (float)__builtin_bit_cast(_Float16, s);
}
static __device__ __forceinline__ float bflo(unsigned d) {
    return __builtin_bit_cast(float, d << 16);
}
static __device__ __forceinline__ float bfhi(unsigned d) {
    return __builtin_bit_cast(float, d & 0xFFFF0000u);
}

// workspace layout (bytes): xtb(8M) | conv(16M) | part(512K) | ss | owT | dwT
#define XTB_BYTES   ((size_t)Bn*HW*64*2)
#define CONV_BYTES  ((size_t)Bn*On*HW*4)
#define PART_BYTES  ((size_t)128*NBLK*4)

// ---------------------------------------------------------------------------
// Prep: blocks 0..511 = NCHW->NHWC bf16 transpose (one (b,h) row each);
//       blocks 512..727 = weight pack bf16 tap-major [o][tap][c].
// ---------------------------------------------------------------------------
__global__ __launch_bounds__(256) void prep_k(
    const float* __restrict__ x,  const float* __restrict__ ow,
    const float* __restrict__ dw, unsigned* __restrict__ xtb,
    short* __restrict__ owT,      short* __restrict__ dwT)
{
    int blk = blockIdx.x;
    int t = threadIdx.x;
    if (blk < 512) {
        int b = blk >> 7, h = blk & 127;
        __shared__ float sT[64 * 133];
        const float* xp = x + (size_t)b * Cn * HW + (size_t)h * Ww;
#pragma unroll
        for (int it = 0; it < 32; ++it) {
            int idx = t + 256 * it;        // c(6b) | w(7b)
            int c = idx >> 7, w = idx & 127;
            sT[c * 133 + w] = xp[(size_t)c * HW + w];
        }
        __syncthreads();
        unsigned* op = xtb + (size_t)blk * Ww * 32;   // 32 dwords (64 bf16)/px
#pragma unroll
        for (int it = 0; it < 16; ++it) {
            int idx = t + 256 * it;        // w(7b) | cp(5b)
            int w = idx >> 5, cp = idx & 31;
            unsigned lo = f2bf(sT[(2 * cp) * 133 + w]);
            unsigned hi = f2bf(sT[(2 * cp + 1) * 133 + w]);
            op[(size_t)w * 32 + cp] = lo | (hi << 16);
        }
    } else {
        int u = (blk - 512) * 4 + (t >> 6);   // 0..863
        int c = t & 63;
        if (u < 288) {
            int o = u / 9, kk = u % 9;
            float v = (o < 27) ? ow[(size_t)o * 576 + c * 9 + kk] : 0.0f;
            owT[(size_t)u * 64 + c] = (short)f2bf(v);
        } else {
            int u2 = u - 288;
            int o = u2 / 9, kk = u2 % 9;
            dwT[(size_t)u2 * 64 + c] = (short)f2bf(dw[(size_t)o * 576 + c * 9 + kk]);
        }
    }
}

// ---------------------------------------------------------------------------
// Fused: offset-conv GEMM -> per-thread bilinear prep -> sampling fill ->
// DCN GEMM -> conv store + BN stats partials (transposed part).
// Block = HALF-row (64 px), grid 1024, 256 thr / 4 waves. x is bf16 NHWC.
// Structure = R2/R4/R9. LESSONS LEDGER:
//  * R3: barrier-free wave-private flip REGRESSED (per-ks global B-frag
//    loads exposed L2 latency on MFMA path). B streams 1/step; A from LDS.
//  * R5 (8-wave block) & R6 (quarter-row/2048 blocks): BOTH ~67-69 us.
//    Achieved residency pinned ~11-13 waves/CU regardless of theoretical
//    cap; occupancy is NOT the lever. Keep half-row/4-wave/1024.
//  * R7 (cross-barrier prefetch) & R8 (register double-buffer): BOTH
//    defeated -- LLVM sinks pure VMEM loads to their use site. Source-level
//    scheduling does not stick on this kernel.
//  * R10: phase-1 load-once/scatter-3 REGRESSED (46->56 us): 528/768
//    threads, divergent conditional scatters; occupancy 33->21%. Keep R9's
//    uniform 6x dwordx4 im2col.
//  * The ONLY lever that pays: FEWER UNIFORM VMEM/LDS ISSUE EVENTS per
//    unit of work (R1 pair-gather, R4 dwordx2, R9 dwordx4 -- width maxed).
// R11 (this round): single variable vs R9 -- prep packed to 8 shorts/unit
// {idx,w00,w01,w10,w11,0,0,0}; phase-3 per-unit broadcast reads b64+b16 ->
// ONE b128; phase-2 writes one b128/unit. LDS 31.4 -> 34.8 KB (4 blocks/CU).
// CRITICAL #1: no __launch_bounds__ min-waves arg (R3 spill disaster).
// CRITICAL #2: wave id readfirstlane'd (R4 divergent-uniform trap).
// MFMA 16x16x32 bf16 (validated R8-R12):
//   A lane=[m=l15][k=quad*8+j]; B lane=[k=quad*8+j][n=l15];
//   D lane=[row=quad*4+r][col=l15].
// LDS: sA 25600 (sOMh 3588 aliased in) + prepP 9216 = 34816 B.
// ---------------------------------------------------------------------------
__global__ __launch_bounds__(256) void dcn_fused_k(
    const unsigned* __restrict__ xtb, const short* __restrict__ owT,
    const float* __restrict__ ob,     const short* __restrict__ dwT,
    float* __restrict__ conv,         float* __restrict__ part)
{
    int raw  = blockIdx.x;
    int blk  = ((raw & 7) << 7) | (raw >> 3);   // b(2b) | h(7b) | half(1b)
    int half = blk & 1;
    int h    = (blk >> 1) & 127;
    int b    = blk >> 8;
    int px0  = half * 64;
    int t    = threadIdx.x;
    int lane = t & 63;
    int quad = lane >> 4;
    int l15  = lane & 15;
    int ul   = lane >> 3;          // eighth-wave unit id (phase 3 fill, 0..7)
    int cl3  = lane & 7;           // dwordx4 (8-channel) group
    int og   = lane >> 3;          // eighth-wave unit id (phase 1 fill)
    int li   = lane & 7;           // dwordx4 lane, phase 1
    int w_s  = __builtin_amdgcn_readfirstlane(t >> 6);   // 0..3 (SGPR)

    __shared__ __align__(16) short sA[64 * KP];               // 25600 B (bf16)
    __shared__ __align__(16) unsigned short prepP[576 * 8];   //  9216 B packed
    short* sOMh = sA;   // 27*OMP+12 = 1794 shorts, aliased (sA dead in phase 2)

    const unsigned* xbd = xtb + (size_t)b * HW * 32;               // dword view
    unsigned* sAd = (unsigned*)sA;                                 // row = 100 dw

    // ================= Phase 1: offset conv GEMM (M=64, N=32) ============
    int nt_o = w_s & 1;
    int mh   = w_s >> 1;
    int o_ow = nt_o * 16 + l15;
    f32x4 oacc[2] = {{0,0,0,0},{0,0,0,0}};

    for (int ck = 0; ck < 3; ++ck) {
        int yy = h + ck - 1;
        bool rowok = ((unsigned)yy < (unsigned)Hh);
        // ---- im2col fill: 192 units (kkl(2b)|px(6b)), 8 lanes x dwordx4 each
#pragma unroll
        for (int it = 0; it < 6; ++it) {
            int unit = (it * 4 + w_s) * 8 + og;   // 0..191
            int kkl = unit >> 6, px = unit & 63;
            int xx = px0 + px + kkl - 1;
            bool valid = rowok && ((unsigned)xx < (unsigned)Ww);
            u32x4 v = {0u, 0u, 0u, 0u};
            if (valid)
                v = *(const u32x4*)&xbd[(((size_t)yy << 7) + xx) * 32 + li * 4];
            *(u32x4*)&sAd[px * 100 + kkl * 32 + li * 4] = v;
        }
        __syncthreads();
#pragma unroll
        for (int ks = 0; ks < 6; ++ks) {
            int kk = ck * 3 + (ks >> 1);
            bf16x8 bfr = *(const bf16x8*)&owT[((size_t)o_ow * 9 + kk) * 64
                                             + (ks & 1) * 32 + quad * 8];
#pragma unroll
            for (int m2 = 0; m2 < 2; ++m2) {
                bf16x8 a = *(const bf16x8*)&sA[(mh * 32 + m2 * 16 + l15) * KP
                                               + ks * 32 + quad * 8];
                oacc[m2] = __builtin_amdgcn_mfma_f32_16x16x32_bf16(a, bfr, oacc[m2], 0, 0, 0);
            }
        }
        __syncthreads();
    }
    // ---- D -> sOMh (+bias), f16; px = (mh*2+m2)*16 + quad*4 + r
    if (o_ow < 27) {
        float bias = ob[o_ow];
#pragma unroll
        for (int m2 = 0; m2 < 2; ++m2) {
            int pxb = (mh * 2 + m2) * 16 + quad * 4;
#pragma unroll
            for (int r = 0; r < 4; ++r)
                sOMh[o_ow * OMP + pxb + r] = f2h(oacc[m2][r] + bias);
        }
    }
    __syncthreads();

    // ================= Phase 2: per-thread bilinear prep -> LDS ==========
    // 576 units = tap(9) x px(64); thread owns u = t, t+256, t+512(<576).
    // Validity factorizes per-axis onto physical rows/cols (yb,yb+1)/(xb,xb+1);
    // corner weight = wr*wc, sigmoid mask folded into wr. Base idx yb*128+xb;
    // corners {+0,+1,+128,+129} always in-bounds. One b128 write per unit.
#pragma unroll
    for (int i = 0; i < 3; ++i) {
        int u = t + 256 * i;
        if (u < 576) {
            int kk = u >> 6, px = u & 63;
            float ox = h2f((short)sOMh[kk * OMP + px]);
            float oy = h2f((short)sOMh[(9 + kk) * OMP + px]);
            float mr = h2f((short)sOMh[(18 + kk) * OMP + px]);
            float m  = 1.0f / (1.0f + __expf(-mr));
            float py  = (float)(h - 1 + (kk / 3)) + oy;
            float pxf = (float)(px0 + px - 1 + (kk % 3)) + ox;
            float y0f = floorf(py), x0f = floorf(pxf);
            int y0 = (int)y0f, x0 = (int)x0f;
            float wy = py - y0f, wx = pxf - x0f;
            int yb = min(max(y0, 0), Hh - 2);
            int xb = min(max(x0, 0), Ww - 2);
            float wr0 = (yb == y0) ? (1.0f - wy) : ((yb     == y0 + 1) ? wy : 0.0f);
            float wr1 = (yb == y0) ? wy          : ((yb + 1 == y0    ) ? (1.0f - wy) : 0.0f);
            float wc0 = (xb == x0) ? (1.0f - wx) : ((xb     == x0 + 1) ? wx : 0.0f);
            float wc1 = (xb == x0) ? wx          : ((xb + 1 == x0    ) ? (1.0f - wx) : 0.0f);
            wr0 *= m; wr1 *= m;
            u16x8 pk8;
            pk8[0] = (unsigned short)(yb * Ww + xb);
            pk8[1] = (unsigned short)f2h(wr0 * wc0);
            pk8[2] = (unsigned short)f2h(wr0 * wc1);
            pk8[3] = (unsigned short)f2h(wr1 * wc0);
            pk8[4] = (unsigned short)f2h(wr1 * wc1);
            pk8[5] = 0; pk8[6] = 0; pk8[7] = 0;
            *(u16x8*)&prepP[u * 8] = pk8;
        }
    }
    __syncthreads();

    // ================= Phase 3: sampling fill + DCN GEMM (M=64, N=64) ====
    // Fill: 8 units per wave-iter (eighth-waves); lane owns 8 CHANNELS
    // (dwordx4). Per unit: ONE b128 broadcast ds_read (packed prep), ONE
    // gather addr chain, 4x dwordx4 (128B/corner coalesced), 32 FMA, 4x
    // v_cvt_pk_bf16_f32, 1 ds_write_b128. 6 iters.
    int o_dw = w_s * 16 + l15;
    f32x4 acc[4] = {{0,0,0,0},{0,0,0,0},{0,0,0,0},{0,0,0,0}};

    for (int ck = 0; ck < 3; ++ck) {
#pragma unroll 3
        for (int it = 0; it < 6; ++it) {
            int unit = (it * 4 + w_s) * 8 + ul;   // 0..191 within ck
            int kkl = unit >> 6, px = unit & 63;
            int uG = ck * 192 + unit;             // global unit id
            u16x8 q = *(const u16x8*)&prepP[uG * 8];     // ONE broadcast b128
            float w00 = h2fu(q[1]);
            float w01 = h2fu(q[2]);
            float w10 = h2fu(q[3]);
            float w11 = h2fu(q[4]);
            const unsigned* p0 = xbd + (size_t)q[0] * 32 + cl3 * 4;
            u32x4 d00 = *(const u32x4*)(p0);
            u32x4 d01 = *(const u32x4*)(p0 + 32);        // col+1 (+128 B)
            u32x4 d10 = *(const u32x4*)(p0 + 4096);      // row+1
            u32x4 d11 = *(const u32x4*)(p0 + 4128);      // row+1, col+1
            u32x4 pkv;
#pragma unroll
            for (int j = 0; j < 4; ++j) {
                float v0 = w00 * bflo(d00[j]) + w01 * bflo(d01[j])
                         + w10 * bflo(d10[j]) + w11 * bflo(d11[j]);
                float v1 = w00 * bfhi(d00[j]) + w01 * bfhi(d01[j])
                         + w10 * bfhi(d10[j]) + w11 * bfhi(d11[j]);
                unsigned pk;
                asm("v_cvt_pk_bf16_f32 %0, %1, %2" : "=v"(pk) : "v"(v0), "v"(v1));
                pkv[j] = pk;
            }
            *(u32x4*)&sAd[px * 100 + kkl * 32 + cl3 * 4] = pkv;
        }
        __syncthreads();
#pragma unroll
        for (int ks = 0; ks < 6; ++ks) {
            int kk = ck * 3 + (ks >> 1);
            bf16x8 bfr = *(const bf16x8*)&dwT[((size_t)o_dw * 9 + kk) * 64
                                              + (ks & 1) * 32 + quad * 8];
#pragma unroll
            for (int mt = 0; mt < 4; ++mt) {
                bf16x8 a = *(const bf16x8*)&sA[(mt * 16 + l15) * KP
                                               + ks * 32 + quad * 8];
                acc[mt] = __builtin_amdgcn_mfma_f32_16x16x32_bf16(a, bfr, acc[mt], 0, 0, 0);
            }
        }
        __syncthreads();
    }

    // ================= Phase 4: store conv + stats partials =================
#pragma unroll
    for (int mt = 0; mt < 4; ++mt) {
        size_t idx = ((size_t)b * On + o_dw) * HW + (size_t)h * Ww + px0 + mt * 16 + quad * 4;
        *(f32x4*)(conv + idx) = acc[mt];
    }
    float s1 = 0.0f, s2 = 0.0f;
#pragma unroll
    for (int mt = 0; mt < 4; ++mt) {
#pragma unroll
        for (int r = 0; r < 4; ++r) {
            float v = acc[mt][r];
            s1 += v;
            s2 += v * v;
        }
    }
    s1 += __shfl_down(s1, 32, 64);  s2 += __shfl_down(s2, 32, 64);
    s1 += __shfl_down(s1, 16, 64);  s2 += __shfl_down(s2, 16, 64);
    if (lane < 16) {
        part[(size_t)o_dw * NBLK + blk]        = s1;
        part[(size_t)(64 + o_dw) * NBLK + blk] = s2;
    }
}

// ---------------------------------------------------------------------------
// Fused BN stats + apply + ReLU.
// Grid 1024: o = idx&63, bq = idx>>6. Each block re-reduces its channel's
// part rows (8 KB, L2-hit) -> sc/sh, then applies BN+ReLU over a 4096-float
// slab of conv.
// ---------------------------------------------------------------------------
__global__ __launch_bounds__(256) void bnstats_k(
    const float* __restrict__ part, const float* __restrict__ gamma,
    const float* __restrict__ beta, const float* __restrict__ conv,
    float* __restrict__ out)
{
    int idx = blockIdx.x;
    int o  = idx & 63;
    int bq = idx >> 6;          // b = bq>>2, q = bq&3
    int t = threadIdx.x;
    float s1 = 0.0f, s2 = 0.0f;
#pragma unroll
    for (int i = 0; i < NBLK / 256; ++i) {
        int j = t + 256 * i;
        s1 += part[(size_t)o * NBLK + j];
        s2 += part[(size_t)(64 + o) * NBLK + j];
    }
#pragma unroll
    for (int off = 32; off > 0; off >>= 1) {
        s1 += __shfl_down(s1, off, 64);
        s2 += __shfl_down(s2, off, 64);
    }
    __shared__ float r1[4], r2[4];
    __shared__ float sc_s, sh_s;
    if ((t & 63) == 0) { r1[t >> 6] = s1; r2[t >> 6] = s2; }
    __syncthreads();
    if (t == 0) {
        float S1 = r1[0] + r1[1] + r1[2] + r1[3];
        float S2 = r2[0] + r2[1] + r2[2] + r2[3];
        float n = (float)(Bn * HW);
        float mu = S1 / n;
        float var = S2 / n - mu * mu;
        float sc = gamma[o] * rsqrtf(var + 1e-5f);
        sc_s = sc;
        sh_s = beta[o] - mu * sc;
    }
    __syncthreads();
    float sc = sc_s, sh = sh_s;
    size_t base = (((size_t)(bq >> 2) * On + o) * HW + (size_t)(bq & 3) * 4096) / 4;
    const float4* cv = (const float4*)conv + base;
    float4* ov = (float4*)out + base;
#pragma unroll
    for (int i = 0; i < 4; ++i) {
        float4 v = cv[t + 256 * i];
        v.x = fmaxf(v.x * sc + sh, 0.0f);
        v.y = fmaxf(v.y * sc + sh, 0.0f);
        v.z = fmaxf(v.z * sc + sh, 0.0f);
        v.w = fmaxf(v.w * sc + sh, 0.0f);
        ov[t + 256 * i] = v;
    }
}

// ---------------------------------------------------------------------------
extern "C" void kernel_launch(void* const* d_in, const int* in_sizes, int n_in,
                              void* d_out, int out_size, void* d_ws, size_t ws_size,
                              hipStream_t stream)
{
    const float* x     = (const float*)d_in[0];
    const float* ow    = (const float*)d_in[1];
    const float* ob    = (const float*)d_in[2];
    const float* dw    = (const float*)d_in[3];
    // d_in[4] = dcn_b: cancels exactly under BN mean subtraction -> unused
    const float* gamma = (const float*)d_in[5];
    const float* beta  = (const float*)d_in[6];

    char* wsb = (char*)d_ws;
    unsigned* xtb = (unsigned*)wsb;
    float* conv = (float*)(wsb + XTB_BYTES);
    float* part = (float*)(wsb + XTB_BYTES + CONV_BYTES);
    short* owT  = (short*)(wsb + XTB_BYTES + CONV_BYTES + PART_BYTES + 512);
    short* dwT  = owT + 288 * 64;

    prep_k     <<<dim3(728),  dim3(256), 0, stream>>>(x, ow, dw, xtb, owT, dwT);
    dcn_fused_k<<<dim3(NBLK), dim3(256), 0, stream>>>(xtb, owT, ob, dwT, conv, part);
    bnstats_k  <<<dim3(1024), dim3(256), 0, stream>>>(part, gamma, beta, conv, (float*)d_out);
}

// Round 13
// 124.062 us; speedup vs baseline: 1.0428x; 1.0428x over previous
//
#include <hip/hip_runtime.h>
#include <math.h>

#define Hh 128
#define Ww 128
#define HW (Hh*Ww)
#define Bn 4
#define Cn 64
#define On 64
#define KP 200                // LDS A-row stride (shorts): 192 data + 8 pad
                              // (==0 mod 8 for 16B ds_read_b128; row stride
                              //  100 dw == 4 mod 32 banks -> 2-way max on
                              //  16-lane span, 4-way on 32-lane span)
#define OMP 66                // padded px stride for sOM (f16), 64 px
#define NBLK 1024             // dcn grid (half-row blocks)
#define NPART 2048            // part columns: blk*2 + px-half (32x32 tiles)

typedef __attribute__((ext_vector_type(8))) short bf16x8;
typedef __attribute__((ext_vector_type(4))) float f32x4;
typedef __attribute__((ext_vector_type(16))) float f32x16;
typedef __attribute__((ext_vector_type(8))) unsigned short u16x8;
typedef __attribute__((ext_vector_type(4))) unsigned u32x4;

// fp32 -> bf16 round-to-nearest-even
static __device__ __forceinline__ unsigned short f2bf(float f) {
    unsigned u = __builtin_bit_cast(unsigned, f);
    u += 0x7FFFu + ((u >> 16) & 1u);
    return (unsigned short)(u >> 16);
}
static __device__ __forceinline__ short f2h(float f) {
    _Float16 h = (_Float16)f;
    return __builtin_bit_cast(short, h);
}
static __device__ __forceinline__ float h2f(short s) {
    return (float)__builtin_bit_cast(_Float16, s);
}
static __device__ __forceinline__ float h2fu(unsigned short s) {
    return (float)__builtin_bit_cast(_Float16, s);
}
static __device__ __forceinline__ float bflo(unsigned d) {
    return __builtin_bit_cast(float, d << 16);
}
static __device__ __forceinline__ float bfhi(unsigned d) {
    return __builtin_bit_cast(float, d & 0xFFFF0000u);
}

// workspace layout (bytes): xtb(8M) | conv(16M) | part(1M) | ss | owT | dwTp
#define XTB_BYTES   ((size_t)Bn*HW*64*2)
#define CONV_BYTES  ((size_t)Bn*On*HW*4)
#define PART_BYTES  ((size_t)128*NPART*4)

// ---------------------------------------------------------------------------
// Prep: blocks 0..511 = NCHW->NHWC bf16 transpose (one (b,h) row each);
//       blocks 512..727 = weight pack. owT: bf16 tap-major [o][tap][c]
//       (phase-1 16x16 frags). dwTp: 32x32-frag layout, plane per
//       (tap kk, ch16-grp g, o-half oh): 512 shorts; within plane lane
//       l=hf*32+om reads 8 shorts at l*8 = B[k=g*16+hf*8+j][o=oh*32+om].
//       R12 BUG FIXED: plane was 512 shorts for ALL o (collision + every
//       wave read o-half 0); now keyed by ((kk*4+g)*2 + oh).
// ---------------------------------------------------------------------------
__global__ __launch_bounds__(256) void prep_k(
    const float* __restrict__ x,  const float* __restrict__ ow,
    const float* __restrict__ dw, unsigned* __restrict__ xtb,
    short* __restrict__ owT,      short* __restrict__ dwTp)
{
    int blk = blockIdx.x;
    int t = threadIdx.x;
    if (blk < 512) {
        int b = blk >> 7, h = blk & 127;
        __shared__ float sT[64 * 133];
        const float* xp = x + (size_t)b * Cn * HW + (size_t)h * Ww;
#pragma unroll
        for (int it = 0; it < 32; ++it) {
            int idx = t + 256 * it;        // c(6b) | w(7b)
            int c = idx >> 7, w = idx & 127;
            sT[c * 133 + w] = xp[(size_t)c * HW + w];
        }
        __syncthreads();
        unsigned* op = xtb + (size_t)blk * Ww * 32;   // 32 dwords (64 bf16)/px
#pragma unroll
        for (int it = 0; it < 16; ++it) {
            int idx = t + 256 * it;        // w(7b) | cp(5b)
            int w = idx >> 5, cp = idx & 31;
            unsigned lo = f2bf(sT[(2 * cp) * 133 + w]);
            unsigned hi = f2bf(sT[(2 * cp + 1) * 133 + w]);
            op[(size_t)w * 32 + cp] = lo | (hi << 16);
        }
    } else {
        int u = (blk - 512) * 4 + (t >> 6);   // 0..863
        int c = t & 63;
        if (u < 288) {
            int o = u / 9, kk = u % 9;
            float v = (o < 27) ? ow[(size_t)o * 576 + c * 9 + kk] : 0.0f;
            owT[(size_t)u * 64 + c] = (short)f2bf(v);
        } else {
            int u2 = u - 288;                 // 0..575 = o*9 + kk
            int o = u2 / 9, kk = u2 % 9;
            short v = (short)f2bf(dw[(size_t)o * 576 + c * 9 + kk]);
            int g = c >> 4, hf = (c >> 3) & 1, j = c & 7;
            int oh = o >> 5, om = o & 31;
            dwTp[(size_t)((kk * 4 + g) * 2 + oh) * 512 + hf * 256 + om * 8 + j] = v;
        }
    }
}

// ---------------------------------------------------------------------------
// Fused: offset-conv GEMM -> per-thread bilinear prep -> sampling fill ->
// DCN GEMM -> conv store + BN stats partials (transposed part).
// Block = HALF-row (64 px), grid 1024, 256 thr / 4 waves. x is bf16 NHWC.
// Structure = R2/R4/R9/R11. LESSONS LEDGER:
//  * R3: per-ks global B-frag loads (4/MFMA) exposed L2 latency on MFMA
//    path. B at 1 L1-hot load per MFMA is fine (R11 does this).
//  * R5/R6: occupancy is NOT the lever (residency pinned ~11-13 waves/CU).
//  * R7/R8: LLVM sinks pure VMEM loads to use; source scheduling dies.
//  * R10: divergent scatter fill regressed. Uniform wide loads only.
//  * R12: dwTp packing collided planes + ignored o-half -> absmax 5.3.
//    Fixed here (plane keyed by ((kk*4+g)*2+oh); load adds (w_s&1) plane).
//  * The lever that pays: FEWER UNIFORM VMEM/LDS ISSUE EVENTS (R1/R4/R9/R11).
// R13: phase-3 GEMM on v_mfma_f32_32x32x16_bf16. Wave owns one 32x32 tile
// (2x2 wave grid over M=64 x N=64). Per ck: 12 B + 12 A + 12 MFMA (was
// 6+24+24) -- A-reads & MFMA instr count HALVED. B from repacked dwTp
// (1KB/wave contiguous, L1 broadcast, 1 load/MFMA = R11's safe ratio).
// Layout note: any k-permutation applied consistently to A and B leaves
// the MFMA dot product invariant; only m/n lane mapping (l&31, standard)
// and C/D mapping (guide-measured m74/m101) must be exact:
//   D lane=[row=(reg&3)+8*(reg>>2)+4*(l>>5)][col=l&31].
// Stats: two waves share an o-range at different px-halves -> part column
// blk*2 + (w_s>>1), NPART=2048 (R5's proven scheme).
// CRITICAL #1: no __launch_bounds__ min-waves arg (R3 spill disaster).
// CRITICAL #2: wave id readfirstlane'd (R4 divergent-uniform trap).
// Phase-1 MFMA 16x16x32 unchanged (validated R8-R12 layouts).
// LDS: sA 25600 (sOMh 3588 aliased in) + prepP 9216 = 34816 B.
// ---------------------------------------------------------------------------
__global__ __launch_bounds__(256) void dcn_fused_k(
    const unsigned* __restrict__ xtb, const short* __restrict__ owT,
    const float* __restrict__ ob,     const short* __restrict__ dwTp,
    float* __restrict__ conv,         float* __restrict__ part)
{
    int raw  = blockIdx.x;
    int blk  = ((raw & 7) << 7) | (raw >> 3);   // b(2b) | h(7b) | half(1b)
    int half = blk & 1;
    int h    = (blk >> 1) & 127;
    int b    = blk >> 8;
    int px0  = half * 64;
    int t    = threadIdx.x;
    int lane = t & 63;
    int quad = lane >> 4;
    int l15  = lane & 15;
    int l31  = lane & 31;          // 32x32 frag row/col
    int hf   = lane >> 5;          // 32x32 frag k-half / px-row-half
    int ul   = lane >> 3;          // eighth-wave unit id (phase 3 fill, 0..7)
    int cl3  = lane & 7;           // dwordx4 (8-channel) group
    int og   = lane >> 3;          // eighth-wave unit id (phase 1 fill)
    int li   = lane & 7;           // dwordx4 lane, phase 1
    int w_s  = __builtin_amdgcn_readfirstlane(t >> 6);   // 0..3 (SGPR)

    __shared__ __align__(16) short sA[64 * KP];               // 25600 B (bf16)
    __shared__ __align__(16) unsigned short prepP[576 * 8];   //  9216 B packed
    short* sOMh = sA;   // 27*OMP+12 = 1794 shorts, aliased (sA dead in phase 2)

    const unsigned* xbd = xtb + (size_t)b * HW * 32;               // dword view
    unsigned* sAd = (unsigned*)sA;                                 // row = 100 dw

    // ================= Phase 1: offset conv GEMM (M=64, N=32) ============
    int nt_o = w_s & 1;
    int mh   = w_s >> 1;
    int o_ow = nt_o * 16 + l15;
    f32x4 oacc[2] = {{0,0,0,0},{0,0,0,0}};

    for (int ck = 0; ck < 3; ++ck) {
        int yy = h + ck - 1;
        bool rowok = ((unsigned)yy < (unsigned)Hh);
        // ---- im2col fill: 192 units (kkl(2b)|px(6b)), 8 lanes x dwordx4 each
#pragma unroll
        for (int it = 0; it < 6; ++it) {
            int unit = (it * 4 + w_s) * 8 + og;   // 0..191
            int kkl = unit >> 6, px = unit & 63;
            int xx = px0 + px + kkl - 1;
            bool valid = rowok && ((unsigned)xx < (unsigned)Ww);
            u32x4 v = {0u, 0u, 0u, 0u};
            if (valid)
                v = *(const u32x4*)&xbd[(((size_t)yy << 7) + xx) * 32 + li * 4];
            *(u32x4*)&sAd[px * 100 + kkl * 32 + li * 4] = v;
        }
        __syncthreads();
#pragma unroll
        for (int ks = 0; ks < 6; ++ks) {
            int kk = ck * 3 + (ks >> 1);
            bf16x8 bfr = *(const bf16x8*)&owT[((size_t)o_ow * 9 + kk) * 64
                                             + (ks & 1) * 32 + quad * 8];
#pragma unroll
            for (int m2 = 0; m2 < 2; ++m2) {
                bf16x8 a = *(const bf16x8*)&sA[(mh * 32 + m2 * 16 + l15) * KP
                                               + ks * 32 + quad * 8];
                oacc[m2] = __builtin_amdgcn_mfma_f32_16x16x32_bf16(a, bfr, oacc[m2], 0, 0, 0);
            }
        }
        __syncthreads();
    }
    // ---- D -> sOMh (+bias), f16; px = (mh*2+m2)*16 + quad*4 + r
    if (o_ow < 27) {
        float bias = ob[o_ow];
#pragma unroll
        for (int m2 = 0; m2 < 2; ++m2) {
            int pxb = (mh * 2 + m2) * 16 + quad * 4;
#pragma unroll
            for (int r = 0; r < 4; ++r)
                sOMh[o_ow * OMP + pxb + r] = f2h(oacc[m2][r] + bias);
        }
    }
    __syncthreads();

    // ================= Phase 2: per-thread bilinear prep -> LDS ==========
    // 576 units = tap(9) x px(64); thread owns u = t, t+256, t+512(<576).
    // Validity factorizes per-axis onto physical rows/cols (yb,yb+1)/(xb,xb+1);
    // corner weight = wr*wc, sigmoid mask folded into wr. Base idx yb*128+xb;
    // corners {+0,+1,+128,+129} always in-bounds. One b128 write per unit.
#pragma unroll
    for (int i = 0; i < 3; ++i) {
        int u = t + 256 * i;
        if (u < 576) {
            int kk = u >> 6, px = u & 63;
            float ox = h2f((short)sOMh[kk * OMP + px]);
            float oy = h2f((short)sOMh[(9 + kk) * OMP + px]);
            float mr = h2f((short)sOMh[(18 + kk) * OMP + px]);
            float m  = 1.0f / (1.0f + __expf(-mr));
            float py  = (float)(h - 1 + (kk / 3)) + oy;
            float pxf = (float)(px0 + px - 1 + (kk % 3)) + ox;
            float y0f = floorf(py), x0f = floorf(pxf);
            int y0 = (int)y0f, x0 = (int)x0f;
            float wy = py - y0f, wx = pxf - x0f;
            int yb = min(max(y0, 0), Hh - 2);
            int xb = min(max(x0, 0), Ww - 2);
            float wr0 = (yb == y0) ? (1.0f - wy) : ((yb     == y0 + 1) ? wy : 0.0f);
            float wr1 = (yb == y0) ? wy          : ((yb + 1 == y0    ) ? (1.0f - wy) : 0.0f);
            float wc0 = (xb == x0) ? (1.0f - wx) : ((xb     == x0 + 1) ? wx : 0.0f);
            float wc1 = (xb == x0) ? wx          : ((xb + 1 == x0    ) ? (1.0f - wx) : 0.0f);
            wr0 *= m; wr1 *= m;
            u16x8 pk8;
            pk8[0] = (unsigned short)(yb * Ww + xb);
            pk8[1] = (unsigned short)f2h(wr0 * wc0);
            pk8[2] = (unsigned short)f2h(wr0 * wc1);
            pk8[3] = (unsigned short)f2h(wr1 * wc0);
            pk8[4] = (unsigned short)f2h(wr1 * wc1);
            pk8[5] = 0; pk8[6] = 0; pk8[7] = 0;
            *(u16x8*)&prepP[u * 8] = pk8;
        }
    }
    __syncthreads();

    // ================= Phase 3: sampling fill + DCN GEMM (M=64, N=64) ====
    // Fill: unchanged (8 units/wave-iter, dwordx4, 6 iters).
    // GEMM: 32x32x16 MFMA; wave tile px [pt,pt+32) x o [ot,ot+32).
    // Per ck: 12 K-steps (kkl = s>>2, ch16-group g = s&3).
    int pt = (w_s >> 1) * 32;
    int oh = w_s & 1;              // o-half (plane selector)
    int ot = oh * 32;
    f32x16 acc = {0,0,0,0,0,0,0,0,0,0,0,0,0,0,0,0};

    for (int ck = 0; ck < 3; ++ck) {
#pragma unroll 3
        for (int it = 0; it < 6; ++it) {
            int unit = (it * 4 + w_s) * 8 + ul;   // 0..191 within ck
            int kkl = unit >> 6, px = unit & 63;
            int uG = ck * 192 + unit;             // global unit id
            u16x8 q = *(const u16x8*)&prepP[uG * 8];     // ONE broadcast b128
            float w00 = h2fu(q[1]);
            float w01 = h2fu(q[2]);
            float w10 = h2fu(q[3]);
            float w11 = h2fu(q[4]);
            const unsigned* p0 = xbd + (size_t)q[0] * 32 + cl3 * 4;
            u32x4 d00 = *(const u32x4*)(p0);
            u32x4 d01 = *(const u32x4*)(p0 + 32);        // col+1 (+128 B)
            u32x4 d10 = *(const u32x4*)(p0 + 4096);      // row+1
            u32x4 d11 = *(const u32x4*)(p0 + 4128);      // row+1, col+1
            u32x4 pkv;
#pragma unroll
            for (int j = 0; j < 4; ++j) {
                float v0 = w00 * bflo(d00[j]) + w01 * bflo(d01[j])
                         + w10 * bflo(d10[j]) + w11 * bflo(d11[j]);
                float v1 = w00 * bfhi(d00[j]) + w01 * bfhi(d01[j])
                         + w10 * bfhi(d10[j]) + w11 * bfhi(d11[j]);
                unsigned pk;
                asm("v_cvt_pk_bf16_f32 %0, %1, %2" : "=v"(pk) : "v"(v0), "v"(v1));
                pkv[j] = pk;
            }
            *(u32x4*)&sAd[px * 100 + kkl * 32 + cl3 * 4] = pkv;
        }
        __syncthreads();
#pragma unroll
        for (int s = 0; s < 12; ++s) {
            int kkl = s >> 2, g = s & 3;
            int kk = ck * 3 + kkl;
            // B: plane (kk,g,oh); lane l=hf*32+l31 reads 8 shorts at l*8 =
            // B[k=g*16+hf*8+j][o=ot+l31]. Wave = 1KB contiguous (L1-hot).
            bf16x8 bfr = *(const bf16x8*)&dwTp[(size_t)((kk * 4 + g) * 2 + oh) * 512
                                               + lane * 8];
            // A: lane m=l31 (px=pt+l31), channel g*16+hf*8+j of tap kkl
            bf16x8 a = *(const bf16x8*)&sA[(pt + l31) * KP + kkl * 64 + g * 16 + hf * 8];
            acc = __builtin_amdgcn_mfma_f32_32x32x16_bf16(a, bfr, acc, 0, 0, 0);
        }
        __syncthreads();
    }

    // ================= Phase 4: store conv + stats partials =================
    // D: row(px) = (reg&3) + 8*(reg>>2) + 4*hf, col(o) = l31.
    int o3 = ot + l31;
#pragma unroll
    for (int rg = 0; rg < 4; ++rg) {
        f32x4 v = {acc[rg * 4 + 0], acc[rg * 4 + 1], acc[rg * 4 + 2], acc[rg * 4 + 3]};
        size_t idx = ((size_t)b * On + o3) * HW + (size_t)h * Ww
                   + px0 + pt + rg * 8 + hf * 4;
        *(f32x4*)(conv + idx) = v;
    }
    // per-o sums over this wave's 32 px: lane holds 16 px, lane+32 the rest.
    float s1 = 0.0f, s2 = 0.0f;
#pragma unroll
    for (int r = 0; r < 16; ++r) {
        float v = acc[r];
        s1 += v;
        s2 += v * v;
    }
    s1 += __shfl_down(s1, 32, 64);
    s2 += __shfl_down(s2, 32, 64);
    if (lane < 32) {
        part[(size_t)o3 * NPART + blk * 2 + (w_s >> 1)]        = s1;
        part[(size_t)(64 + o3) * NPART + blk * 2 + (w_s >> 1)] = s2;
    }
}

// ---------------------------------------------------------------------------
// Fused BN stats + apply + ReLU.
// Grid 1024: o = idx&63, bq = idx>>6. Each block re-reduces its channel's
// part rows (16 KB, L2-hit) -> sc/sh, then applies BN+ReLU over a 4096-float
// slab of conv.
// ---------------------------------------------------------------------------
__global__ __launch_bounds__(256) void bnstats_k(
    const float* __restrict__ part, const float* __restrict__ gamma,
    const float* __restrict__ beta, const float* __restrict__ conv,
    float* __restrict__ out)
{
    int idx = blockIdx.x;
    int o  = idx & 63;
    int bq = idx >> 6;          // b = bq>>2, q = bq&3
    int t = threadIdx.x;
    float s1 = 0.0f, s2 = 0.0f;
#pragma unroll
    for (int i = 0; i < NPART / 256; ++i) {
        int j = t + 256 * i;
        s1 += part[(size_t)o * NPART + j];
        s2 += part[(size_t)(64 + o) * NPART + j];
    }
#pragma unroll
    for (int off = 32; off > 0; off >>= 1) {
        s1 += __shfl_down(s1, off, 64);
        s2 += __shfl_down(s2, off, 64);
    }
    __shared__ float r1[4], r2[4];
    __shared__ float sc_s, sh_s;
    if ((t & 63) == 0) { r1[t >> 6] = s1; r2[t >> 6] = s2; }
    __syncthreads();
    if (t == 0) {
        float S1 = r1[0] + r1[1] + r1[2] + r1[3];
        float S2 = r2[0] + r2[1] + r2[2] + r2[3];
        float n = (float)(Bn * HW);
        float mu = S1 / n;
        float var = S2 / n - mu * mu;
        float sc = gamma[o] * rsqrtf(var + 1e-5f);
        sc_s = sc;
        sh_s = beta[o] - mu * sc;
    }
    __syncthreads();
    float sc = sc_s, sh = sh_s;
    size_t base = (((size_t)(bq >> 2) * On + o) * HW + (size_t)(bq & 3) * 4096) / 4;
    const float4* cv = (const float4*)conv + base;
    float4* ov = (float4*)out + base;
#pragma unroll
    for (int i = 0; i < 4; ++i) {
        float4 v = cv[t + 256 * i];
        v.x = fmaxf(v.x * sc + sh, 0.0f);
        v.y = fmaxf(v.y * sc + sh, 0.0f);
        v.z = fmaxf(v.z * sc + sh, 0.0f);
        v.w = fmaxf(v.w * sc + sh, 0.0f);
        ov[t + 256 * i] = v;
    }
}

// ---------------------------------------------------------------------------
extern "C" void kernel_launch(void* const* d_in, const int* in_sizes, int n_in,
                              void* d_out, int out_size, void* d_ws, size_t ws_size,
                              hipStream_t stream)
{
    const float* x     = (const float*)d_in[0];
    const float* ow    = (const float*)d_in[1];
    const float* ob    = (const float*)d_in[2];
    const float* dw    = (const float*)d_in[3];
    // d_in[4] = dcn_b: cancels exactly under BN mean subtraction -> unused
    const float* gamma = (const float*)d_in[5];
    const float* beta  = (const float*)d_in[6];

    char* wsb = (char*)d_ws;
    unsigned* xtb = (unsigned*)wsb;
    float* conv = (float*)(wsb + XTB_BYTES);
    float* part = (float*)(wsb + XTB_BYTES + CONV_BYTES);
    short* owT  = (short*)(wsb + XTB_BYTES + CONV_BYTES + PART_BYTES + 512);
    short* dwTp = owT + 288 * 64;           // 36864 shorts (73728 B)

    prep_k     <<<dim3(728),  dim3(256), 0, stream>>>(x, ow, dw, xtb, owT, dwTp);
    dcn_fused_k<<<dim3(NBLK), dim3(256), 0, stream>>>(xtb, owT, ob, dwTp, conv, part);
    bnstats_k  <<<dim3(1024), dim3(256), 0, stream>>>(part, gamma, beta, conv, (float*)d_out);
}